// Round 1
// baseline (259.870 us; speedup 1.0000x reference)
//
#include <hip/hip_runtime.h>

#define NQ     12
#define DIM    4096      // 2^12
#define NPAIR  2048
#define BLOCK  256
#define NPARAM 240       // 12*4*5
#define NL     4

__device__ __forceinline__ float2 cmul(float2 a, float2 b) {
    return make_float2(a.x*b.x - a.y*b.y, a.x*b.y + a.y*b.x);
}

__global__ __launch_bounds__(BLOCK)
void qfe_kernel(const float* __restrict__ params,
                const float* __restrict__ inputs,
                float* __restrict__ out) {
    const int b = blockIdx.x;
    const int t = threadIdx.x;
    const int lane = t & 63;
    const int wid  = t >> 6;

    __shared__ float2 st[DIM];        // 32 KB state
    __shared__ float2 g1[60][4];      // 12 embed RY + 48 fused layer matrices
    __shared__ float2 gcrx[96];       // (cos, sin) for 4*24 CRX gates
    __shared__ float redx[4], redy[4], redz[4];

    // ---- precompute gate matrices ----
    if (t < 12) {
        // RY embedding on qubit t, angle inputs[b, t % 12] (d == 12)
        float a = inputs[b * NQ + t] * 0.5f;
        float c = cosf(a), s = sinf(a);
        g1[t][0] = make_float2(c, 0.f);
        g1[t][1] = make_float2(-s, 0.f);
        g1[t][2] = make_float2(s, 0.f);
        g1[t][3] = make_float2(c, 0.f);
    } else if (t < 60) {
        int g = t - 12;
        int l = g / 12, q = g % 12;
        const float* pp = params + b * NPARAM + l * 60 + q * 3;
        float ax = pp[0] * 0.5f, ay = pp[1] * 0.5f, az = pp[2] * 0.5f;
        float cx = cosf(ax), sx = sinf(ax);
        float cy = cosf(ay), sy = sinf(ay);
        float cz = cosf(az), sz = sinf(az);
        // Ry * Rx
        float2 a00 = make_float2( cy*cx,  sy*sx);
        float2 a01 = make_float2(-sy*cx, -cy*sx);
        float2 a10 = make_float2( sy*cx, -cy*sx);
        float2 a11 = make_float2( cy*cx, -sy*sx);
        // Rz rows: e^{-i az} row0, e^{+i az} row1
        float2 e0 = make_float2(cz, -sz);
        float2 e1 = make_float2(cz,  sz);
        g1[t][0] = cmul(e0, a00);
        g1[t][1] = cmul(e0, a01);
        g1[t][2] = cmul(e1, a10);
        g1[t][3] = cmul(e1, a11);
    }
    if (t < 96) {
        int l = t / 24, j = t % 24;
        float a = params[b * NPARAM + l * 60 + 36 + j] * 0.5f;
        gcrx[t] = make_float2(cosf(a), sinf(a));
    }

    // ---- init state |0...0> ----
    for (int i = t; i < DIM; i += BLOCK) st[i] = make_float2(0.f, 0.f);
    if (t == 0) st[0] = make_float2(1.f, 0.f);
    __syncthreads();

    // ---- gate sweeps ----
    // 1q generic sweep lambda-ish via macro-free inline loop
    auto sweep1q = [&](int gidx, int q) {
        int pos = 11 - q;
        float2 u00 = g1[gidx][0], u01 = g1[gidx][1];
        float2 u10 = g1[gidx][2], u11 = g1[gidx][3];
        int mask = (1 << pos) - 1;
        int bit  = 1 << pos;
        for (int k = t; k < NPAIR; k += BLOCK) {
            int i0 = ((k & ~mask) << 1) | (k & mask);
            int i1 = i0 | bit;
            float2 s0 = st[i0], s1 = st[i1];
            float2 n0 = make_float2(
                u00.x*s0.x - u00.y*s0.y + u01.x*s1.x - u01.y*s1.y,
                u00.x*s0.y + u00.y*s0.x + u01.x*s1.y + u01.y*s1.x);
            float2 n1 = make_float2(
                u10.x*s0.x - u10.y*s0.y + u11.x*s1.x - u11.y*s1.y,
                u10.x*s0.y + u10.y*s0.x + u11.x*s1.y + u11.y*s1.x);
            st[i0] = n0;
            st[i1] = n1;
        }
        __syncthreads();
    };

    auto sweepcrx = [&](int cidx, int cq, int tq) {
        float c = gcrx[cidx].x, s = gcrx[cidx].y;
        int pc = 11 - cq, pt = 11 - tq;
        int plo = pc < pt ? pc : pt;
        int phi = pc < pt ? pt : pc;
        int mlo = (1 << plo) - 1;
        int mhi = (1 << phi) - 1;
        int cbit = 1 << pc, tbit = 1 << pt;
        for (int k = t; k < 1024; k += BLOCK) {
            int t1 = ((k & ~mlo) << 1) | (k & mlo);
            int t2 = ((t1 & ~mhi) << 1) | (t1 & mhi);
            int i0 = t2 | cbit;        // ctrl bit = 1, tgt bit = 0
            int i1 = i0 | tbit;
            float2 s0 = st[i0], s1 = st[i1];
            // RX: n0 = c*s0 - i*s*s1 ; n1 = c*s1 - i*s*s0
            st[i0] = make_float2(c*s0.x + s*s1.y, c*s0.y - s*s1.x);
            st[i1] = make_float2(c*s1.x + s*s0.y, c*s1.y - s*s0.x);
        }
        __syncthreads();
    };

    // RY input embedding
    for (int q = 0; q < NQ; ++q) sweep1q(q, q);

    int gi = 12, ci = 0;
    for (int l = 0; l < NL; ++l) {
        for (int q = 0; q < NQ; ++q) sweep1q(gi++, q);
        for (int j = 0; j < 24; ++j) {
            int cq, tq;
            if (j < 12) { cq = j;      tq = (j + 1) % NQ; }
            else        { int i = 23 - j; cq = i; tq = (i + 11) % NQ; }
            sweepcrx(ci++, cq, tq);
        }
    }

    // ---- expectation values ----
    for (int q = 0; q < NQ; ++q) {
        int pos = 11 - q;
        int mask = (1 << pos) - 1;
        int bit  = 1 << pos;
        float lx = 0.f, ly = 0.f, lz = 0.f;
        for (int k = t; k < NPAIR; k += BLOCK) {
            int i0 = ((k & ~mask) << 1) | (k & mask);
            int i1 = i0 | bit;
            float2 s0 = st[i0], s1 = st[i1];
            lx += s0.x*s1.x + s0.y*s1.y;            // Re(conj(s0)*s1)
            ly += s0.x*s1.y - s0.y*s1.x;            // Im(conj(s0)*s1)
            lz += (s0.x*s0.x + s0.y*s0.y) - (s1.x*s1.x + s1.y*s1.y);
        }
        #pragma unroll
        for (int off = 32; off > 0; off >>= 1) {
            lx += __shfl_down(lx, off);
            ly += __shfl_down(ly, off);
            lz += __shfl_down(lz, off);
        }
        if (lane == 0) { redx[wid] = lx; redy[wid] = ly; redz[wid] = lz; }
        __syncthreads();
        if (t == 0) {
            float X = redx[0] + redx[1] + redx[2] + redx[3];
            float Y = redy[0] + redy[1] + redy[2] + redy[3];
            float Z = redz[0] + redz[1] + redz[2] + redz[3];
            out[b * 36 + q]      = 2.f * X;
            out[b * 36 + 12 + q] = 2.f * Y;
            out[b * 36 + 24 + q] = Z;
        }
        __syncthreads();
    }
}

extern "C" void kernel_launch(void* const* d_in, const int* in_sizes, int n_in,
                              void* d_out, int out_size, void* d_ws, size_t ws_size,
                              hipStream_t stream) {
    const float* params = (const float*)d_in[0];   // (1024, 240) float32
    const float* inputs = (const float*)d_in[1];   // (1024, 12)  float32
    float* out = (float*)d_out;                    // (1024, 36)  float32
    qfe_kernel<<<1024, BLOCK, 0, stream>>>(params, inputs, out);
}